// Round 7
// baseline (332.427 us; speedup 1.0000x reference)
//
#include <hip/hip_runtime.h>
#include <hip/hip_bf16.h>
#include <stdint.h>

// Problem: out = x_norm + dropout(relu(LN(x) @ W1) @ W2), B=4,S=2048,D=2048
#define M_DIM 8192   // B*S
#define N_DIM 2048
#define K_DIM 2048

typedef __bf16 bf16x8_t __attribute__((ext_vector_type(8)));
typedef float f32x4_t __attribute__((ext_vector_type(4)));

// ---------------- threefry2x32, JAX partitionable path, key=(0,1) -------------
// bits(j) = o0^o1 of threefry2x32(key=(0,1), ctr=(0, j)); keep iff bits < 0xC0000000.
// Verified: absmax 0.0625 -> mask exact.
__device__ __forceinline__ unsigned tf_rotl(unsigned x, int r) {
  return (x << r) | (x >> (32 - r));
}
__device__ __forceinline__ unsigned threefry_mask_bits(unsigned ctr) {
  unsigned x0 = 0u, x1 = ctr;
  const unsigned ks0 = 0u, ks1 = 1u, ks2 = 0x1BD11BDBu;
  x0 += ks0; x1 += ks1;
#define TFR(r) { x0 += x1; x1 = tf_rotl(x1, (r)); x1 ^= x0; }
  TFR(13) TFR(15) TFR(26) TFR(6)
  x0 += ks1; x1 += ks2 + 1u;
  TFR(17) TFR(29) TFR(16) TFR(24)
  x0 += ks2; x1 += ks0 + 2u;
  TFR(13) TFR(15) TFR(26) TFR(6)
  x0 += ks0; x1 += ks1 + 3u;
  TFR(17) TFR(29) TFR(16) TFR(24)
  x0 += ks1; x1 += ks2 + 4u;
  TFR(13) TFR(15) TFR(26) TFR(6)
  x0 += ks2; x1 += ks0 + 5u;
#undef TFR
  return x0 ^ x1;
}

// ---------------- async global->LDS, 16B per lane -----------------------------
__device__ __forceinline__ void gload_lds16(const __hip_bfloat16* g, unsigned short* l) {
  __builtin_amdgcn_global_load_lds(
      (const __attribute__((address_space(1))) unsigned int*)g,
      (__attribute__((address_space(3))) unsigned int*)l,
      16, 0, 0);
}

// ---------------- W [K][N] fp32 -> Wt [N][K] bf16 -----------------------------
__global__ __launch_bounds__(256) void wt_kernel(
    const float* __restrict__ W1, const float* __restrict__ W2,
    __hip_bfloat16* __restrict__ W1t, __hip_bfloat16* __restrict__ W2t) {
  __shared__ float tile[32][33];
  const float* src = blockIdx.z ? W2 : W1;
  __hip_bfloat16* dst = blockIdx.z ? W2t : W1t;
  int x = blockIdx.x * 32 + threadIdx.x;
  int y = blockIdx.y * 32 + threadIdx.y;
#pragma unroll
  for (int i = 0; i < 32; i += 8)
    tile[threadIdx.y + i][threadIdx.x] = src[(size_t)(y + i) * N_DIM + x];
  __syncthreads();
  int xo = blockIdx.y * 32 + threadIdx.x;
  int yo = blockIdx.x * 32 + threadIdx.y;
#pragma unroll
  for (int i = 0; i < 32; i += 8)
    dst[(size_t)(yo + i) * K_DIM + xo] = __float2bfloat16(tile[threadIdx.x][threadIdx.y + i]);
}

// ---------------- LayerNorm (no affine) -> bf16 -------------------------------
__global__ __launch_bounds__(256) void ln_kernel(const float* __restrict__ X,
                                                 __hip_bfloat16* __restrict__ Xn) {
  const int row = blockIdx.x;
  const float4* xv = (const float4*)(X + (size_t)row * K_DIM);
  float4 v0 = xv[threadIdx.x];
  float4 v1 = xv[threadIdx.x + 256];
  float s  = v0.x + v0.y + v0.z + v0.w + v1.x + v1.y + v1.z + v1.w;
  float ss = v0.x*v0.x + v0.y*v0.y + v0.z*v0.z + v0.w*v0.w
           + v1.x*v1.x + v1.y*v1.y + v1.z*v1.z + v1.w*v1.w;
#pragma unroll
  for (int off = 32; off > 0; off >>= 1) {
    s  += __shfl_xor(s, off);
    ss += __shfl_xor(ss, off);
  }
  __shared__ float rs[4], rss[4];
  const int wave = threadIdx.x >> 6;
  if ((threadIdx.x & 63) == 0) { rs[wave] = s; rss[wave] = ss; }
  __syncthreads();
  float S  = rs[0] + rs[1] + rs[2] + rs[3];
  float SS = rss[0] + rss[1] + rss[2] + rss[3];
  float mean = S * (1.0f / 2048.0f);
  float var  = SS * (1.0f / 2048.0f) - mean * mean;
  float rstd = 1.0f / sqrtf(var + 1e-6f);
  float vv[8] = {v0.x, v0.y, v0.z, v0.w, v1.x, v1.y, v1.z, v1.w};
  unsigned short o[8];
#pragma unroll
  for (int i = 0; i < 8; i++) {
    __hip_bfloat16 b = __float2bfloat16((vv[i] - mean) * rstd);
    o[i] = *(unsigned short*)&b;
  }
  ushort4* dst = (ushort4*)(Xn + (size_t)row * K_DIM);
  dst[threadIdx.x]       = make_ushort4(o[0], o[1], o[2], o[3]);
  dst[threadIdx.x + 256] = make_ushort4(o[4], o[5], o[6], o[7]);
}

// ---------------- 128x128 MFMA GEMM, BK=32 dbuf, counted-vmcnt pipeline -------
// Round-6 post-mortem: counted vmcnt on the BK=64 dbuf gained only 4%
// (106us, MfmaUtil 28%). Cycle budget: ~4000 cy/tile/block, MFMA pipe busy
// ~31%/CU at 2 blocks/CU -- the CU is WAVE-STARVED (Occupancy 20%, capped by
// 64KB LDS). The 900-TF m97-family reference runs 3+ blocks/CU and wins via
// cross-block overlap (m114). Single change vs round 6: BK 64->32 halves LDS
// to 32KB -> 4 blocks/CU (LDS allows 5, ~108 arch VGPR allows 4 waves/SIMD).
// Grid 1024 blocks = exactly 1 resident generation (256 CU x 4).
// LDS rows are 32 elems (64B) = 4 slots of 16B. Slot s of row r holds global
// chunk s^((r>>1)&3): staging source permutation (l&3)^((l>>3)&3) is its
// inverse under the linear global_load_lds write (both-sides rule); on the
// read side every 8-lane phase group of ds_read_b128 hits all 8 bank-quads
// (enumerated: rows 0-7 / 8-15 x any k-chunk -> {0,4,1,5,2,6,3,7}) => 0 bank
// conflicts. Per K-32 tile: 8 ds_read_b128 + 16 MFMA (same per-K ratio as
// round 6); staging = 4 gloads (A 8KB + B 8KB, chunks of 1KB = 16 rows).
// Pipeline per tile t (buf = t&1): COMPUTE(buf); s_barrier; STAGE(buf, t+2);
// vmcnt(4) [only the stage just issued may remain in flight => tile t+1
// fully landed]; s_barrier. Drain vmcnt(0) only at tile 62; tile 63 computes
// only. K-chunk accumulation order unchanged -> bit-identical output.
// EPI=0: H=relu(A@B)->bf16. EPI=1: out=Xn+dropout/0.75.
template <int EPI>
__global__ __launch_bounds__(256, 4) void gemm128(
    const __hip_bfloat16* __restrict__ A,
    const __hip_bfloat16* __restrict__ Bt,
    const __hip_bfloat16* __restrict__ Xn,   // EPI=1 residual
    __hip_bfloat16* __restrict__ Hout,       // EPI=0 output
    float* __restrict__ Fout) {              // EPI=1 output
  __shared__ unsigned short As[2][128 * 32];  // 2 x 8 KB
  __shared__ unsigned short Bs[2][128 * 32];  // 2 x 8 KB
  const int tid  = threadIdx.x;
  const int lane = tid & 63;
  const int wave = tid >> 6;
  const int wm = wave >> 1, wn = wave & 1;
  // grid: x walks M (fastest) -> consecutive blocks share the B panel in L2.
  const int mBase = blockIdx.x * 128;
  const int nBase = blockIdx.y * 128;

  f32x4_t acc[4][4];
#pragma unroll
  for (int i = 0; i < 4; i++)
#pragma unroll
    for (int j = 0; j < 4; j++) acc[i][j] = (f32x4_t){0.f, 0.f, 0.f, 0.f};

  // ---- staging: 8 KB per matrix per tile = 8 chunks of 1 KB (16 rows x 64B).
  // wave w loads chunks {w, w+4} of A and of B (4 gloads/thread/tile).
  // lane l: row-in-chunk l>>2, slot l&3, source k-chunk (l&3)^((l>>3)&3).
  const int rowIn  = lane >> 2;                            // 0..15 within chunk
  const int csrc   = ((lane & 3) ^ ((lane >> 3) & 3)) << 3; // swizzled src elems
  const __hip_bfloat16* aSrc[2];
  const __hip_bfloat16* bSrc[2];
  int sDst[2];
#pragma unroll
  for (int j = 0; j < 2; j++) {
    const int ca = wave + 4 * j;                           // chunk index 0..7
    aSrc[j] = A  + (size_t)(mBase + 16 * ca + rowIn) * K_DIM + csrc;
    bSrc[j] = Bt + (size_t)(nBase + 16 * ca + rowIn) * K_DIM + csrc;
    sDst[j] = ca * 512;                                    // shorts: 1KB per chunk
  }

  // ---- fragment read addresses (slot = k-chunk ^ ((row>>1)&3); wm*64 and
  // mi*16 are multiples of 16, so the row-dependent term reduces to fr)
  const int fr = lane & 15;
  const int fq = lane >> 4;                                // k-chunk 0..3
  const int ck = (fq ^ ((fr >> 1) & 3)) << 3;              // swizzled, shorts
  const int rowOffA = (wm * 64 + fr) * 32;
  const int rowOffB = (wn * 64 + fr) * 32;

#define STAGE(buf, k0)                                        \
  {                                                           \
    _Pragma("unroll")                                         \
    for (int j = 0; j < 2; j++) {                             \
      gload_lds16(aSrc[j] + (k0), &As[buf][sDst[j]]);         \
      gload_lds16(bSrc[j] + (k0), &Bs[buf][sDst[j]]);         \
    }                                                         \
  }

#define COMPUTE(buf)                                                            \
  {                                                                             \
    bf16x8_t af[4], bfr[4];                                                     \
    _Pragma("unroll")                                                           \
    for (int i = 0; i < 4; i++) af[i]  = *(const bf16x8_t*)(&As[buf][rowOffA + i * 512 + ck]); \
    _Pragma("unroll")                                                           \
    for (int i = 0; i < 4; i++) bfr[i] = *(const bf16x8_t*)(&Bs[buf][rowOffB + i * 512 + ck]); \
    _Pragma("unroll")                                                           \
    for (int mi = 0; mi < 4; mi++)                                              \
      _Pragma("unroll")                                                         \
      for (int ni = 0; ni < 4; ni++)                                            \
        acc[mi][ni] = __builtin_amdgcn_mfma_f32_16x16x32_bf16(af[mi], bfr[ni], acc[mi][ni], 0, 0, 0); \
  }

#define BAR() __builtin_amdgcn_s_barrier()
#define VMW(n)  asm volatile("s_waitcnt vmcnt(" #n ")" ::: "memory")

  // TSTEP(BUF, STG, KNEXT, VMODE): one K-32 tile on buffer BUF (literal).
  // STG: stage tile t+2 at elem offset KNEXT into BUF. VMODE 0 = VMW(4)
  // counted, 1 = VMW(0) drain (tile 62), 2 = none (tile 63).
#define TSTEP(BUF, STG, KNEXT, VMODE)                                    \
  {                                                                      \
    COMPUTE(BUF)                                                         \
    BAR();                        /* all waves done reading BUF */       \
    if (STG) { STAGE(BUF, KNEXT) }                                       \
    if ((VMODE) == 0) { VMW(4); } else if ((VMODE) == 1) { VMW(0); }     \
    if ((VMODE) != 2) { BAR(); }  /* next buffer published */            \
  }

  // ---- prologue: tiles 0 and 1 staged; VMW(4) -> tile0's 4 gloads landed.
  STAGE(0, 0)
  STAGE(1, 32)
  VMW(4);
  BAR();

  // 64 K-tiles. Pairs (t, t+1) with literal buffers; tile t stages t+2.
  // k0 = 0..1920 step 64 covers tiles 0..61; tile 62 drains; 63 computes only.
  for (int k0 = 0; k0 < 1984; k0 += 64) {
    TSTEP(0, 1, k0 + 64, 0)
    TSTEP(1, 1, k0 + 96, 0)
  }
  TSTEP(0, 0, 0, 1)
  TSTEP(1, 0, 0, 2)

#undef TSTEP
#undef STAGE
#undef COMPUTE
#undef BAR
#undef VMW

  // epilogue: D row = fq*4 + reg, col = fr (m89-verified C/D layout)
  const int mRow = mBase + wm * 64;
  const int nCol = nBase + wn * 64;
#pragma unroll
  for (int mi = 0; mi < 4; mi++) {
#pragma unroll
    for (int ni = 0; ni < 4; ni++) {
      const int n  = nCol + ni * 16 + fr;
      const int m0 = mRow + mi * 16 + fq * 4;
#pragma unroll
      for (int r = 0; r < 4; r++) {
        float v = acc[mi][ni][r];
        size_t j = (size_t)(m0 + r) * N_DIM + n;
        if (EPI == 0) {
          Hout[j] = __float2bfloat16(fmaxf(v, 0.0f));
        } else {
          unsigned bits = threefry_mask_bits((unsigned)j);
          float y  = (bits < 0xC0000000u) ? v * (1.0f / 0.75f) : 0.0f;
          Fout[j]  = __bfloat162float(Xn[j]) + y;
        }
      }
    }
  }
}

extern "C" void kernel_launch(void* const* d_in, const int* in_sizes, int n_in,
                              void* d_out, int out_size, void* d_ws, size_t ws_size,
                              hipStream_t stream) {
  (void)in_sizes; (void)n_in; (void)out_size; (void)ws_size;
  const float* X  = (const float*)d_in[0];
  const float* W1 = (const float*)d_in[1];
  const float* W2 = (const float*)d_in[2];
  float* out = (float*)d_out;

  unsigned char* ws = (unsigned char*)d_ws;
  __hip_bfloat16* Xn  = (__hip_bfloat16*)(ws);                       // 32 MB
  __hip_bfloat16* H   = (__hip_bfloat16*)(ws + ((size_t)32 << 20));  // 32 MB
  __hip_bfloat16* W1t = (__hip_bfloat16*)(ws + ((size_t)64 << 20));  //  8 MB
  __hip_bfloat16* W2t = (__hip_bfloat16*)(ws + ((size_t)72 << 20));  //  8 MB

  wt_kernel<<<dim3(64, 64, 2), dim3(32, 8, 1), 0, stream>>>(W1, W2, W1t, W2t);
  ln_kernel<<<M_DIM, 256, 0, stream>>>(X, Xn);
  gemm128<0><<<dim3(M_DIM / 128, N_DIM / 128), 256, 0, stream>>>(Xn, W1t, nullptr, H, nullptr);
  gemm128<1><<<dim3(M_DIM / 128, N_DIM / 128), 256, 0, stream>>>(H, W2t, Xn, nullptr, out);
}

// Round 8
// 317.932 us; speedup vs baseline: 1.0456x; 1.0456x over previous
//
#include <hip/hip_runtime.h>
#include <hip/hip_bf16.h>
#include <stdint.h>

// Problem: out = x_norm + dropout(relu(LN(x) @ W1) @ W2), B=4,S=2048,D=2048
#define M_DIM 8192   // B*S
#define N_DIM 2048
#define K_DIM 2048

typedef __bf16 bf16x8_t __attribute__((ext_vector_type(8)));
typedef float f32x4_t __attribute__((ext_vector_type(4)));
typedef float f32x16_t __attribute__((ext_vector_type(16)));

// ---------------- threefry2x32, JAX partitionable path, key=(0,1) -------------
// bits(j) = o0^o1 of threefry2x32(key=(0,1), ctr=(0, j)); keep iff bits < 0xC0000000.
// Verified: absmax 0.0625 -> mask exact.
__device__ __forceinline__ unsigned tf_rotl(unsigned x, int r) {
  return (x << r) | (x >> (32 - r));
}
__device__ __forceinline__ unsigned threefry_mask_bits(unsigned ctr) {
  unsigned x0 = 0u, x1 = ctr;
  const unsigned ks0 = 0u, ks1 = 1u, ks2 = 0x1BD11BDBu;
  x0 += ks0; x1 += ks1;
#define TFR(r) { x0 += x1; x1 = tf_rotl(x1, (r)); x1 ^= x0; }
  TFR(13) TFR(15) TFR(26) TFR(6)
  x0 += ks1; x1 += ks2 + 1u;
  TFR(17) TFR(29) TFR(16) TFR(24)
  x0 += ks2; x1 += ks0 + 2u;
  TFR(13) TFR(15) TFR(26) TFR(6)
  x0 += ks0; x1 += ks1 + 3u;
  TFR(17) TFR(29) TFR(16) TFR(24)
  x0 += ks1; x1 += ks2 + 4u;
  TFR(13) TFR(15) TFR(26) TFR(6)
  x0 += ks2; x1 += ks0 + 5u;
#undef TFR
  return x0 ^ x1;
}

// ---------------- async global->LDS, 16B per lane -----------------------------
__device__ __forceinline__ void gload_lds16(const __hip_bfloat16* g, unsigned short* l) {
  __builtin_amdgcn_global_load_lds(
      (const __attribute__((address_space(1))) unsigned int*)g,
      (__attribute__((address_space(3))) unsigned int*)l,
      16, 0, 0);
}

// ---------------- merged prep: LN (blocks 0..8191) + W transpose (8192..16383)
// One launch instead of two: the two BW-bound phases execute concurrently and
// one kernel boundary is removed. Work per block identical to the previous
// separate kernels (ln_kernel / wt_kernel), just index-remapped to 256 1D thr.
__global__ __launch_bounds__(256) void prep_kernel(
    const float* __restrict__ X,  __hip_bfloat16* __restrict__ Xn,
    const float* __restrict__ W1, const float* __restrict__ W2,
    __hip_bfloat16* __restrict__ W1t, __hip_bfloat16* __restrict__ W2t) {
  const int bid = blockIdx.x;
  if (bid < M_DIM) {
    // ---- LayerNorm row (no affine) -> bf16
    const int row = bid;
    const float4* xv = (const float4*)(X + (size_t)row * K_DIM);
    float4 v0 = xv[threadIdx.x];
    float4 v1 = xv[threadIdx.x + 256];
    float s  = v0.x + v0.y + v0.z + v0.w + v1.x + v1.y + v1.z + v1.w;
    float ss = v0.x*v0.x + v0.y*v0.y + v0.z*v0.z + v0.w*v0.w
             + v1.x*v1.x + v1.y*v1.y + v1.z*v1.z + v1.w*v1.w;
#pragma unroll
    for (int off = 32; off > 0; off >>= 1) {
      s  += __shfl_xor(s, off);
      ss += __shfl_xor(ss, off);
    }
    __shared__ float rs[4], rss[4];
    const int wave = threadIdx.x >> 6;
    if ((threadIdx.x & 63) == 0) { rs[wave] = s; rss[wave] = ss; }
    __syncthreads();
    float S  = rs[0] + rs[1] + rs[2] + rs[3];
    float SS = rss[0] + rss[1] + rss[2] + rss[3];
    float mean = S * (1.0f / 2048.0f);
    float var  = SS * (1.0f / 2048.0f) - mean * mean;
    float rstd = 1.0f / sqrtf(var + 1e-6f);
    float vv[8] = {v0.x, v0.y, v0.z, v0.w, v1.x, v1.y, v1.z, v1.w};
    unsigned short o[8];
#pragma unroll
    for (int i = 0; i < 8; i++) {
      __hip_bfloat16 b = __float2bfloat16((vv[i] - mean) * rstd);
      o[i] = *(unsigned short*)&b;
    }
    ushort4* dst = (ushort4*)(Xn + (size_t)row * K_DIM);
    dst[threadIdx.x]       = make_ushort4(o[0], o[1], o[2], o[3]);
    dst[threadIdx.x + 256] = make_ushort4(o[4], o[5], o[6], o[7]);
  } else {
    // ---- W [K][N] fp32 -> Wt [N][K] bf16, 32x32 tile
    const int t = bid - M_DIM;
    const int z  = t >> 12;           // 0: W1, 1: W2  (4096 tiles each)
    const int r  = t & 4095;
    const int bx = r & 63;
    const int by = r >> 6;
    const int tx = threadIdx.x & 31;
    const int ty = threadIdx.x >> 5;  // 0..7
    __shared__ float tile[32][33];
    const float* src = z ? W2 : W1;
    __hip_bfloat16* dst = z ? W2t : W1t;
    int x = bx * 32 + tx;
    int y = by * 32 + ty;
#pragma unroll
    for (int i = 0; i < 32; i += 8)
      tile[ty + i][tx] = src[(size_t)(y + i) * N_DIM + x];
    __syncthreads();
    int xo = by * 32 + tx;
    int yo = bx * 32 + ty;
#pragma unroll
    for (int i = 0; i < 32; i += 8)
      dst[(size_t)(yo + i) * K_DIM + xo] = __float2bfloat16(tile[tx][ty + i]);
  }
}

// ---------------- 128x128 MFMA GEMM, BK=64 dbuf, counted vmcnt, 32x32x16 ------
// Round-6 base (best: 106us/GEMM; BK=64 dbuf, counted VMW(8), 2 blocks/CU,
// 0 bank conflicts) with the MFMA shape switched 16x16x32 -> 32x32x16:
// the 32x32 shape runs ~15-21% more FLOP/cycle on the matrix pipe (ubench
// 2382 vs 2075 TF) and quarters MFMA instruction count (16/tile/wave @ 32K
// FLOP each). Same LDS layout/swizzle (64-elem rows, slot s of row r holds
// chunk s^(r&7)); new read pattern: lane l, m-tile mt, k-slice ks(0..3):
// row = 32*mt + (l&31), chunk = 2*ks + (l>>5), slot = chunk^(row&7). Per
// 16-lane group: 2 lanes per bank-quad -- identical aliasing to the measured-
// 0-conflict 16x16 pattern (2-way is free, m136). 16 ds_read_b128 + 16 MFMA
// per wave per tile; acc = 2x2 x f32x16 = 64 AGPR.
// Pipeline per tile t (buf=t&1): COMPUTE(buf); s_barrier; STAGE(buf, t+2);
// vmcnt(8) [only the just-issued stage may remain -> tile t+1 fully landed];
// s_barrier. Drain vmcnt(0) only at tile 30; tile 31 computes only.
// C/D layout (m74/m101-verified): col = lane&31, row = (reg&3) + 8*(reg>>2)
// + 4*(lane>>5). EPI=0: H=relu(A@B)->bf16. EPI=1: out=Xn+dropout/0.75.
template <int EPI>
__global__ __launch_bounds__(256) void gemm128(
    const __hip_bfloat16* __restrict__ A,
    const __hip_bfloat16* __restrict__ Bt,
    const __hip_bfloat16* __restrict__ Xn,   // EPI=1 residual
    __hip_bfloat16* __restrict__ Hout,       // EPI=0 output
    float* __restrict__ Fout) {              // EPI=1 output
  __shared__ unsigned short As[2][128 * 64];  // 32 KB
  __shared__ unsigned short Bs[2][128 * 64];  // 32 KB
  const int tid  = threadIdx.x;
  const int lane = tid & 63;
  const int wave = tid >> 6;
  const int wm = wave >> 1, wn = wave & 1;
  // grid: x walks M (fastest) -> consecutive blocks share the B panel in L2.
  const int mBase = blockIdx.x * 128;
  const int nBase = blockIdx.y * 128;

  f32x16_t acc[2][2];
#pragma unroll
  for (int i = 0; i < 2; i++)
#pragma unroll
    for (int j = 0; j < 2; j++)
#pragma unroll
      for (int e = 0; e < 16; e++) acc[i][j][e] = 0.0f;

  // ---- staging: 16 KB per matrix per stage = 16 chunks of 1 KB (8 rows x 128B).
  // wave w loads chunks {w, w+4, w+8, w+12} of A and of B (8 gloads/stage).
  // lane l covers row 8*ca + (l>>3), source k-chunk (l&7)^((l>>3)&7) (swizzle).
  const int rowIn  = lane >> 3;                       // 0..7 within chunk
  const int csrc   = ((lane & 7) ^ (rowIn & 7)) << 3; // swizzled src k-elem offset
  const __hip_bfloat16* aSrc[4];
  const __hip_bfloat16* bSrc[4];
  int sDst[4];
#pragma unroll
  for (int j = 0; j < 4; j++) {
    const int ca = wave + 4 * j;                      // chunk index 0..15
    aSrc[j] = A  + (size_t)(mBase + 8 * ca + rowIn) * K_DIM + csrc;
    bSrc[j] = Bt + (size_t)(nBase + 8 * ca + rowIn) * K_DIM + csrc;
    sDst[j] = ca * 512;                               // shorts: 1KB per chunk
  }

  // ---- fragment read addresses for 32x32x16 (slot = chunk ^ (row&7))
  const int r32 = lane & 31;            // row/col within 32-tile
  const int kg  = lane >> 5;            // 0/1: which 8-elem k-group
  const int sw  = r32 & 7;              // row&7 (wm*64, mt*32 are 0 mod 8)
  const int rowA0 = (wm * 64 +      r32) * 64;   // mt=0, shorts
  const int rowA1 = (wm * 64 + 32 + r32) * 64;   // mt=1
  const int rowB0 = (wn * 64 +      r32) * 64;   // nt=0
  const int rowB1 = (wn * 64 + 32 + r32) * 64;   // nt=1

#define STAGE(buf, k0)                                        \
  {                                                           \
    _Pragma("unroll")                                         \
    for (int j = 0; j < 4; j++) {                             \
      gload_lds16(aSrc[j] + (k0), &As[buf][sDst[j]]);         \
      gload_lds16(bSrc[j] + (k0), &Bs[buf][sDst[j]]);         \
    }                                                         \
  }

  // per k-slice ks (K=16): chunk = 2*ks + kg, slot = chunk^sw, shorts <<3
#define COMPUTE(buf)                                                            \
  {                                                                             \
    _Pragma("unroll")                                                           \
    for (int ks = 0; ks < 4; ks++) {                                            \
      const int ck = (((ks << 1) | kg) ^ sw) << 3;                              \
      bf16x8_t a0 = *(const bf16x8_t*)(&As[buf][rowA0 + ck]);                   \
      bf16x8_t a1 = *(const bf16x8_t*)(&As[buf][rowA1 + ck]);                   \
      bf16x8_t b0 = *(const bf16x8_t*)(&Bs[buf][rowB0 + ck]);                   \
      bf16x8_t b1 = *(const bf16x8_t*)(&Bs[buf][rowB1 + ck]);                   \
      acc[0][0] = __builtin_amdgcn_mfma_f32_32x32x16_bf16(a0, b0, acc[0][0], 0, 0, 0); \
      acc[0][1] = __builtin_amdgcn_mfma_f32_32x32x16_bf16(a0, b1, acc[0][1], 0, 0, 0); \
      acc[1][0] = __builtin_amdgcn_mfma_f32_32x32x16_bf16(a1, b0, acc[1][0], 0, 0, 0); \
      acc[1][1] = __builtin_amdgcn_mfma_f32_32x32x16_bf16(a1, b1, acc[1][1], 0, 0, 0); \
    }                                                                           \
  }

#define BAR() __builtin_amdgcn_s_barrier()
#define VMW(n)  asm volatile("s_waitcnt vmcnt(" #n ")" ::: "memory")

  // TSTEP(BUF, STG, KNEXT, VMODE): one K-64 tile on buffer BUF (literal).
  // STG: stage tile t+2 at offset KNEXT into BUF. VMODE 0 = VMW(8) counted,
  // 1 = VMW(0) drain (tile 30), 2 = none (tile 31).
#define TSTEP(BUF, STG, KNEXT, VMODE)                                    \
  {                                                                      \
    COMPUTE(BUF)                                                         \
    BAR();                        /* all waves done reading BUF */       \
    if (STG) { STAGE(BUF, KNEXT) }                                       \
    if ((VMODE) == 0) { VMW(8); } else if ((VMODE) == 1) { VMW(0); }     \
    if ((VMODE) != 2) { BAR(); }  /* next buffer published */            \
  }

  // ---- prologue: tiles 0 and 1 staged; VMW(8) -> tile0's 8 gloads landed.
  STAGE(0, 0)
  STAGE(1, 64)
  VMW(8);
  BAR();

  // 32 K-tiles. Pairs (t, t+1) with literal buffers; tile t stages t+2.
  // t=0..29 full pipeline; t=30 drains (stage(31) outstanding); t=31 compute only.
  for (int k0 = 0; k0 < 1920; k0 += 128) {
    TSTEP(0, 1, k0 + 128, 0)
    TSTEP(1, 1, k0 + 192, 0)
  }
  TSTEP(0, 0, 0, 1)
  TSTEP(1, 0, 0, 2)

#undef TSTEP
#undef STAGE
#undef COMPUTE
#undef BAR
#undef VMW

  // epilogue: 32x32 C/D layout: col = r32, row = (r&3) + 8*(r>>2) + 4*kg
  const int mRow = mBase + wm * 64;
  const int nCol = nBase + wn * 64;
#pragma unroll
  for (int mt = 0; mt < 2; mt++) {
#pragma unroll
    for (int nt = 0; nt < 2; nt++) {
      const int col = nCol + nt * 32 + r32;
#pragma unroll
      for (int r = 0; r < 16; r++) {
        const int row = mRow + mt * 32 + (r & 3) + ((r >> 2) << 3) + (kg << 2);
        float v = acc[mt][nt][r];
        size_t j = (size_t)row * N_DIM + col;
        if (EPI == 0) {
          Hout[j] = __float2bfloat16(fmaxf(v, 0.0f));
        } else {
          unsigned bits = threefry_mask_bits((unsigned)j);
          float y  = (bits < 0xC0000000u) ? v * (1.0f / 0.75f) : 0.0f;
          Fout[j]  = __bfloat162float(Xn[j]) + y;
        }
      }
    }
  }
}

extern "C" void kernel_launch(void* const* d_in, const int* in_sizes, int n_in,
                              void* d_out, int out_size, void* d_ws, size_t ws_size,
                              hipStream_t stream) {
  (void)in_sizes; (void)n_in; (void)out_size; (void)ws_size;
  const float* X  = (const float*)d_in[0];
  const float* W1 = (const float*)d_in[1];
  const float* W2 = (const float*)d_in[2];
  float* out = (float*)d_out;

  unsigned char* ws = (unsigned char*)d_ws;
  __hip_bfloat16* Xn  = (__hip_bfloat16*)(ws);                       // 32 MB
  __hip_bfloat16* H   = (__hip_bfloat16*)(ws + ((size_t)32 << 20));  // 32 MB
  __hip_bfloat16* W1t = (__hip_bfloat16*)(ws + ((size_t)64 << 20));  //  8 MB
  __hip_bfloat16* W2t = (__hip_bfloat16*)(ws + ((size_t)72 << 20));  //  8 MB

  prep_kernel<<<dim3(2 * M_DIM, 1, 1), 256, 0, stream>>>(X, Xn, W1, W2, W1t, W2t);
  gemm128<0><<<dim3(M_DIM / 128, N_DIM / 128), 256, 0, stream>>>(Xn, W1t, nullptr, H, nullptr);
  gemm128<1><<<dim3(M_DIM / 128, N_DIM / 128), 256, 0, stream>>>(H, W2t, Xn, nullptr, out);
}